// Round 1
// baseline (573.695 us; speedup 1.0000x reference)
//
#include <hip/hip_runtime.h>
#include <hip/hip_bf16.h>

// Problem constants (from setup_inputs)
constexpr int B    = 32;
constexpr int N    = 1568;
constexpr int N0   = 3136;
constexpr int Nt   = 784;
constexpr int Cin  = 256;
constexpr int Cout = 512;
constexpr int H    = 56;
constexpr int W    = 56;
constexpr int HW   = H * W;        // 3136
constexpr int Ho   = 28;
constexpr int Wo   = 28;
constexpr int HWo  = Ho * Wo;      // 784
constexpr int RR   = B * Nt;       // 25088 rows into the GEMM

// Workspace layout (float offsets). The big dense map is reused for num/den
// after the conv has consumed it.
constexpr size_t MAP_F   = (size_t)B * HW * Cin;            // 25,690,112
constexpr size_t CNT_F   = MAP_F;                           // B*HW counts
constexpr size_t RCP_F   = CNT_F + (size_t)B * HW;
constexpr size_t CONV_F  = RCP_F + (size_t)B * HW;          // B*HWo*Cin conv out
constexpr size_t WFT_F   = CONV_F + (size_t)B * HWo * Cin;  // folded weight [Cin,Cout]
constexpr size_t BIAS_F  = WFT_F + (size_t)Cin * Cout;      // Cout
constexpr size_t S1SUM_F = BIAS_F + Cout;                   // Cin
constexpr size_t S1SQ_F  = S1SUM_F + Cin;                   // Cin
constexpr size_t S2SUM_F = S1SQ_F + Cin;                    // Cout
constexpr size_t S2SQ_F  = S2SUM_F + Cout;                  // Cout
constexpr size_t NUMEND_F = (size_t)RR * Cin;               // den lives right after num

__device__ __forceinline__ int pix_of(float t, float scale) {
    // matches: round(clip(t,-1,1)*0.5+0.5)*(dim-1)) with half-to-even rounding.
    t = fminf(fmaxf(t, -1.0f), 1.0f);
    float u = __fadd_rn(__fmul_rn(t, 0.5f), 0.5f);   // no fma contraction
    return (int)rintf(__fmul_rn(u, scale));          // rintf = round-half-even
}

// ---- K1: scatter tokens into dense map (sum) + counts -----------------------
__global__ void k_scatter_map(const float* __restrict__ x, const float* __restrict__ loc,
                              const int* __restrict__ idx_agg,
                              float* __restrict__ map, float* __restrict__ cnt) {
    int bi = blockIdx.x;                  // b*N0 + i
    int b  = bi / N0;
    int c  = threadIdx.x;                 // 0..255
    float lx = loc[(size_t)bi * 2 + 0];
    float ly = loc[(size_t)bi * 2 + 1];
    int ix = pix_of(lx, (float)(W - 1));
    int iy = pix_of(ly, (float)(H - 1));
    int p  = iy * W + ix;
    int s  = idx_agg[bi];
    float v = x[((size_t)b * N + s) * Cin + c];
    atomicAdd(&map[((size_t)b * HW + p) * Cin + c], v);
    if (c == 0) atomicAdd(&cnt[(size_t)b * HW + p], 1.0f);
}

// ---- K2: reciprocal of (count + eps) per pixel ------------------------------
__global__ void k_rcp(const float* __restrict__ cnt, float* __restrict__ rcp) {
    int j = blockIdx.x * 256 + threadIdx.x;
    if (j < B * HW) rcp[j] = 1.0f / (cnt[j] + 1e-6f);
}

// ---- K3: 3x3 depthwise conv, stride 2, pad 1, channels-last -----------------
// Fuses the map normalization (multiply by per-pixel rcp).
__global__ void k_conv(const float* __restrict__ map, const float* __restrict__ rcp,
                       const float* __restrict__ dww, float* __restrict__ out) {
    int blk = blockIdx.x;                 // b*HWo + oy*Wo + ox
    int c   = threadIdx.x;
    int b   = blk / HWo;
    int rem = blk - b * HWo;
    int oy  = rem / Wo;
    int ox  = rem - oy * Wo;
    float w[9];
#pragma unroll
    for (int k = 0; k < 9; ++k) w[k] = dww[c * 9 + k];
    float acc = 0.0f;
#pragma unroll
    for (int ky = 0; ky < 3; ++ky) {
        int iy = oy * 2 - 1 + ky;
        if (iy < 0 || iy >= H) continue;
#pragma unroll
        for (int kx = 0; kx < 3; ++kx) {
            int ix = ox * 2 - 1 + kx;
            if (ix < 0 || ix >= W) continue;
            size_t pp = (size_t)b * HW + iy * W + ix;
            acc = fmaf(map[pp * Cin + c] * rcp[pp], w[ky * 3 + kx], acc);
        }
    }
    out[(size_t)blk * Cin + c] = acc;
}

// ---- K5: fused map2token gather + token_downup skip, single scatter ---------
// y_num += w * (pix + skip_w*src); den += w  (denominators identical in ref)
__global__ void k_scatter_tok(const float* __restrict__ x, const float* __restrict__ loc,
                              const int* __restrict__ idx_agg, const int* __restrict__ idx_agg_t,
                              const float* __restrict__ wt, const float* __restrict__ convout,
                              const float* __restrict__ skip_w,
                              float* __restrict__ num, float* __restrict__ den) {
    int bi = blockIdx.x;
    int b  = bi / N0;
    int c  = threadIdx.x;
    float lx = loc[(size_t)bi * 2 + 0];
    float ly = loc[(size_t)bi * 2 + 1];
    int ix = pix_of(lx, (float)(Wo - 1));
    int iy = pix_of(ly, (float)(Ho - 1));
    int p  = iy * Wo + ix;
    int s  = idx_agg[bi];
    int t  = idx_agg_t[bi];
    float w = wt[bi];
    float pix = convout[((size_t)b * HWo + p) * Cin + c];
    float src = x[((size_t)b * N + s) * Cin + c];
    float v = w * (pix + skip_w[c] * src);
    atomicAdd(&num[((size_t)b * Nt + t) * Cin + c], v);
    if (c == 0) atomicAdd(&den[(size_t)b * Nt + t], w);
}

// ---- K6: y = num/(den+eps) in place + BN1 per-channel sums ------------------
__global__ void k_y_stats(float* __restrict__ y, const float* __restrict__ den,
                          float* __restrict__ s1sum, float* __restrict__ s1sq) {
    int c = threadIdx.x;
    float sum = 0.0f, sq = 0.0f;
    for (int r = blockIdx.x; r < RR; r += gridDim.x) {
        float d = 1.0f / (den[r] + 1e-6f);
        float v = y[(size_t)r * Cin + c] * d;
        y[(size_t)r * Cin + c] = v;
        sum += v;
        sq  = fmaf(v, v, sq);
    }
    atomicAdd(&s1sum[c], sum);
    atomicAdd(&s1sq[c], sq);
}

// ---- K7: fold BN1 into GEMM weight (transposed) + bias ----------------------
__global__ void k_fold(const float* __restrict__ s1sum, const float* __restrict__ s1sq,
                       const float* __restrict__ g1, const float* __restrict__ b1,
                       const float* __restrict__ convw, float* __restrict__ wft,
                       float* __restrict__ bias) {
    int o = blockIdx.x;      // 0..511
    int c = threadIdx.x;     // 0..255
    const float inv = 1.0f / (float)RR;
    float mu  = s1sum[c] * inv;
    float var = s1sq[c] * inv - mu * mu;
    float a   = g1[c] / sqrtf(var + 1e-5f);
    float bs  = b1[c] - mu * a;
    float wv  = convw[(size_t)o * Cin + c];
    wft[(size_t)c * Cout + o] = wv * a;
    __shared__ float red[256];
    red[c] = wv * bs;
    __syncthreads();
    for (int st = 128; st > 0; st >>= 1) {
        if (c < st) red[c] += red[c + st];
        __syncthreads();
    }
    if (c == 0) bias[o] = red[0];
}

// ---- K8: fp32 GEMM  z[R,Cout] = y[R,Cin] @ wft[Cin,Cout] + bias -------------
__global__ __launch_bounds__(256) void k_gemm(const float* __restrict__ A,
                                              const float* __restrict__ Bm,
                                              const float* __restrict__ bias,
                                              float* __restrict__ Cmat) {
    constexpr int BM = 64, BN = 64, BK = 16;
    __shared__ float As[BK][BM];
    __shared__ float Bs[BK][BN];
    int m0 = blockIdx.x * BM;
    int n0 = blockIdx.y * BN;
    int t  = threadIdx.x;
    int tx = t & 15, ty = t >> 4;
    float acc[4][4] = {};
    for (int k0 = 0; k0 < Cin; k0 += BK) {
        {   // A tile: 64x16, one float4 per thread
            int row = t >> 2;
            int kk  = (t & 3) * 4;
            const float4 v = *(const float4*)&A[(size_t)(m0 + row) * Cin + k0 + kk];
            As[kk + 0][row] = v.x; As[kk + 1][row] = v.y;
            As[kk + 2][row] = v.z; As[kk + 3][row] = v.w;
        }
        {   // B tile: 16x64, one float4 per thread
            int kk  = t >> 4;
            int col = (t & 15) * 4;
            const float4 v = *(const float4*)&Bm[(size_t)(k0 + kk) * Cout + n0 + col];
            *(float4*)&Bs[kk][col] = v;
        }
        __syncthreads();
#pragma unroll
        for (int k = 0; k < BK; ++k) {
            float a[4], bb[4];
#pragma unroll
            for (int i = 0; i < 4; ++i) a[i] = As[k][ty * 4 + i];
#pragma unroll
            for (int j = 0; j < 4; ++j) bb[j] = Bs[k][tx * 4 + j];
#pragma unroll
            for (int i = 0; i < 4; ++i)
#pragma unroll
                for (int j = 0; j < 4; ++j) acc[i][j] = fmaf(a[i], bb[j], acc[i][j]);
        }
        __syncthreads();
    }
#pragma unroll
    for (int i = 0; i < 4; ++i) {
        int m = m0 + ty * 4 + i;
        int n = n0 + tx * 4;
        float4 o4;
        o4.x = acc[i][0] + bias[n + 0];
        o4.y = acc[i][1] + bias[n + 1];
        o4.z = acc[i][2] + bias[n + 2];
        o4.w = acc[i][3] + bias[n + 3];
        *(float4*)&Cmat[(size_t)m * Cout + n] = o4;
    }
}

// ---- K9: BN2 per-channel sums over z ----------------------------------------
__global__ void k_stats2(const float* __restrict__ z, float* __restrict__ s2sum,
                         float* __restrict__ s2sq) {
    int o = threadIdx.x;   // 0..511
    float sum = 0.0f, sq = 0.0f;
    for (int r = blockIdx.x; r < RR; r += gridDim.x) {
        float v = z[(size_t)r * Cout + o];
        sum += v;
        sq  = fmaf(v, v, sq);
    }
    atomicAdd(&s2sum[o], sum);
    atomicAdd(&s2sq[o], sq);
}

// ---- K10: BN2 normalize + ReLU in place -------------------------------------
__global__ void k_final(float* __restrict__ z, const float* __restrict__ s2sum,
                        const float* __restrict__ s2sq, const float* __restrict__ g2,
                        const float* __restrict__ b2) {
    size_t j = (size_t)blockIdx.x * 256 + threadIdx.x;
    int o = (int)(j & (Cout - 1));
    const float inv = 1.0f / (float)RR;
    float mu  = s2sum[o] * inv;
    float var = s2sq[o] * inv - mu * mu;
    float v = (z[j] - mu) / sqrtf(var + 1e-5f) * g2[o] + b2[o];
    z[j] = fmaxf(v, 0.0f);
}

extern "C" void kernel_launch(void* const* d_in, const int* in_sizes, int n_in,
                              void* d_out, int out_size, void* d_ws, size_t ws_size,
                              hipStream_t stream) {
    const float* x     = (const float*)d_in[0];
    const float* loc   = (const float*)d_in[1];
    const int*   idxa  = (const int*)d_in[2];
    // d_in[3] agg_weight: unused by reference
    const int*   idxt  = (const int*)d_in[4];
    const float* wt    = (const float*)d_in[5];
    // d_in[6..8] H, W, Nt scalars: compile-time constants here
    const float* dww   = (const float*)d_in[9];
    const float* skipw = (const float*)d_in[10];
    const float* convw = (const float*)d_in[11];
    const float* g1    = (const float*)d_in[12];
    const float* b1    = (const float*)d_in[13];
    const float* g2    = (const float*)d_in[14];
    const float* b2    = (const float*)d_in[15];

    float* ws    = (float*)d_ws;
    float* map   = ws;                 // [B*HW, Cin]; reused as num/den later
    float* cnt   = ws + CNT_F;
    float* rcp   = ws + RCP_F;
    float* conv  = ws + CONV_F;        // [B*HWo, Cin]
    float* wft   = ws + WFT_F;         // [Cin, Cout]
    float* bias  = ws + BIAS_F;
    float* s1sum = ws + S1SUM_F;
    float* s1sq  = ws + S1SQ_F;
    float* s2sum = ws + S2SUM_F;
    float* s2sq  = ws + S2SQ_F;
    float* num   = ws;                 // aliases map (map dead after conv)
    float* den   = ws + NUMEND_F;
    float* z     = (float*)d_out;      // GEMM out, BN2 in place

    // zero map + cnt (contiguous)
    hipMemsetAsync(map, 0, (MAP_F + (size_t)B * HW) * sizeof(float), stream);
    // zero all stats buffers (contiguous: s1sum..s2sq)
    hipMemsetAsync(s1sum, 0, (size_t)(Cin + Cin + Cout + Cout) * sizeof(float), stream);

    k_scatter_map<<<B * N0, Cin, 0, stream>>>(x, loc, idxa, map, cnt);
    k_rcp<<<(B * HW + 255) / 256, 256, 0, stream>>>(cnt, rcp);
    k_conv<<<B * HWo, Cin, 0, stream>>>(map, rcp, dww, conv);

    // map region dead now; reuse for num/den
    hipMemsetAsync(num, 0, (NUMEND_F + (size_t)RR) * sizeof(float), stream);
    k_scatter_tok<<<B * N0, Cin, 0, stream>>>(x, loc, idxa, idxt, wt, conv, skipw, num, den);
    k_y_stats<<<256, Cin, 0, stream>>>(num, den, s1sum, s1sq);
    k_fold<<<Cout, Cin, 0, stream>>>(s1sum, s1sq, g1, b1, convw, wft, bias);

    dim3 gg(RR / 64, Cout / 64);
    k_gemm<<<gg, 256, 0, stream>>>(num, wft, bias, z);
    k_stats2<<<256, Cout, 0, stream>>>(z, s2sum, s2sq);
    k_final<<<(int)(((size_t)RR * Cout) / 256), 256, 0, stream>>>(z, s2sum, s2sq, g2, b2);
}

// Round 2
// 364.354 us; speedup vs baseline: 1.5746x; 1.5746x over previous
//
#include <hip/hip_runtime.h>

// Problem constants
constexpr int B    = 32;
constexpr int N    = 1568;
constexpr int N0   = 3136;
constexpr int Nt   = 784;
constexpr int Cin  = 256;
constexpr int Cout = 512;
constexpr int H    = 56;
constexpr int W    = 56;
constexpr int HW   = 3136;
constexpr int Ho   = 28;
constexpr int Wo   = 28;
constexpr int HWo  = 784;
constexpr int RR   = B * Nt;      // 25088 GEMM rows
constexpr int NE   = B * N0;      // 100352 scatter entries (per list)
constexpr int NBP  = B * HW;      // 100352 pixel bins
constexpr int NBT  = B * Nt;      // 25088 token bins
constexpr int NB   = NBP + NBT;   // 125440 total bins
constexpr int NCHUNK = NB / 256;  // 490 (exact)

// Workspace layout in 4-byte words. hist+stats contiguous for one memset.
constexpr size_t W_HIST = 0;                       // NB ints (zeroed)
constexpr size_t W_S1SUM = NB;                     // Cin
constexpr size_t W_S1SQ  = W_S1SUM + Cin;          // Cin
constexpr size_t W_S2SUM = W_S1SQ + Cin;           // Cout
constexpr size_t W_S2SQ  = W_S2SUM + Cout;         // Cout (end of memset region)
constexpr size_t W_OFF  = NB + 1536;               // NB+1 ints (pad to +8)
constexpr size_t W_CUR  = W_OFF + NB + 8;          // NB ints
constexpr size_t W_P56  = W_CUR + NB;              // NE ints
constexpr size_t W_P28  = W_P56 + NE;              // NE ints
constexpr size_t W_BSUM = W_P28 + NE;              // 512 ints
constexpr size_t W_SRTS = W_BSUM + 512;            // NE ints (pixel-bucketed src tokens)
constexpr size_t W_STS  = W_SRTS + NE;             // NE ints
constexpr size_t W_STP  = W_STS + NE;              // NE ints
constexpr size_t W_STW  = W_STP + NE;              // NE floats
constexpr size_t W_CONV = W_STW + NE;              // B*HWo*Cin floats
constexpr size_t W_YBF  = W_CONV + (size_t)B * HWo * Cin;   // RR*Cin bf16 (half words)
constexpr size_t W_WFB  = W_YBF + (size_t)RR * Cin / 2;     // Cout*Cin bf16
constexpr size_t W_BIAS = W_WFB + (size_t)Cout * Cin / 2;   // Cout floats

__device__ __forceinline__ int pix_of(float t, float scale) {
    t = fminf(fmaxf(t, -1.0f), 1.0f);
    float u = __fadd_rn(__fmul_rn(t, 0.5f), 0.5f);   // no fma contraction
    return (int)rintf(__fmul_rn(u, scale));          // round-half-even, matches jnp.round
}

__device__ __forceinline__ unsigned short f2bf(float f) {
    unsigned int u = __float_as_uint(f);
    u = (u + 0x7fffu + ((u >> 16) & 1u)) >> 16;      // RNE
    return (unsigned short)u;
}
__device__ __forceinline__ float bf2f(unsigned short h) {
    return __uint_as_float(((unsigned int)h) << 16);
}

// ---- sort phase: histogram over both bin spaces -----------------------------
__global__ void k_hist(const float* __restrict__ loc, const int* __restrict__ idxt,
                       int* __restrict__ hist, int* __restrict__ p56a, int* __restrict__ p28a) {
    int i = blockIdx.x * 256 + threadIdx.x;
    if (i >= NE) return;
    int b = i / N0;
    float lx = loc[(size_t)2 * i], ly = loc[(size_t)2 * i + 1];
    int p56 = pix_of(ly, 55.0f) * W + pix_of(lx, 55.0f);
    int p28 = pix_of(ly, 27.0f) * Wo + pix_of(lx, 27.0f);
    p56a[i] = p56; p28a[i] = p28;
    atomicAdd(&hist[b * HW + p56], 1);
    atomicAdd(&hist[NBP + b * Nt + idxt[i]], 1);
}

__global__ void k_scanA(const int* __restrict__ hist, int* __restrict__ bsum) {
    __shared__ int sm[256];
    int i = blockIdx.x * 256 + threadIdx.x;
    sm[threadIdx.x] = hist[i];
    __syncthreads();
    for (int d = 128; d > 0; d >>= 1) {
        if (threadIdx.x < d) sm[threadIdx.x] += sm[threadIdx.x + d];
        __syncthreads();
    }
    if (threadIdx.x == 0) bsum[blockIdx.x] = sm[0];
}

__global__ void k_scanB(int* __restrict__ bsum) {   // exclusive scan of NCHUNK sums
    __shared__ int sm[512];
    int t = threadIdx.x;
    int v = (t < NCHUNK) ? bsum[t] : 0;
    sm[t] = v; __syncthreads();
    for (int d = 1; d < 512; d <<= 1) {
        int u = (t >= d) ? sm[t - d] : 0;
        __syncthreads();
        sm[t] += u;
        __syncthreads();
    }
    if (t < NCHUNK) bsum[t] = sm[t] - v;
}

__global__ void k_scanC(const int* __restrict__ hist, const int* __restrict__ bsum,
                        int* __restrict__ off, int* __restrict__ cur) {
    __shared__ int sm[256];
    int t = threadIdx.x;
    int i = blockIdx.x * 256 + t;
    int v = hist[i];
    sm[t] = v; __syncthreads();
    for (int d = 1; d < 256; d <<= 1) {
        int u = (t >= d) ? sm[t - d] : 0;
        __syncthreads();
        sm[t] += u;
        __syncthreads();
    }
    int excl = bsum[blockIdx.x] + sm[t] - v;
    off[i] = excl; cur[i] = excl;
    if (i == NB - 1) off[NB] = excl + v;
}

__global__ void k_scatteridx(const int* __restrict__ p56a, const int* __restrict__ p28a,
                             const int* __restrict__ idxa, const int* __restrict__ idxt,
                             const float* __restrict__ wt, int* __restrict__ cur,
                             int* __restrict__ srtS, int* __restrict__ sTs,
                             int* __restrict__ sTp, float* __restrict__ sTw) {
    int i = blockIdx.x * 256 + threadIdx.x;
    if (i >= NE) return;
    int b = i / N0;
    int s = idxa[i];
    int posP = atomicAdd(&cur[b * HW + p56a[i]], 1);
    srtS[posP] = s;
    int posT = atomicAdd(&cur[NBP + b * Nt + idxt[i]], 1) - NE;
    sTs[posT] = s; sTp[posT] = p28a[i]; sTw[posT] = wt[i];
}

// ---- fused token2map + depthwise 3x3 s2 conv as pure gather -----------------
__global__ __launch_bounds__(256) void k_gconv(const float* __restrict__ x,
        const int* __restrict__ off, const int* __restrict__ srtS,
        const float* __restrict__ dww, float* __restrict__ conv) {
    int blk = blockIdx.x;            // b*HWo + oy*Wo + ox
    int c   = threadIdx.x;
    int b   = blk / HWo;
    int rem = blk - b * HWo;
    int oy  = rem / Wo;
    int ox  = rem - oy * Wo;
    float wv[9];
#pragma unroll
    for (int k = 0; k < 9; ++k) wv[k] = dww[c * 9 + k];
    float acc = 0.0f;
#pragma unroll
    for (int ky = 0; ky < 3; ++ky) {
        int iy = oy * 2 - 1 + ky;
        if (iy < 0 || iy >= H) continue;
#pragma unroll
        for (int kx = 0; kx < 3; ++kx) {
            int ix = ox * 2 - 1 + kx;
            if (ix < 0 || ix >= W) continue;
            int bin = b * HW + iy * W + ix;
            int st = off[bin], en = off[bin + 1];
            if (st == en) continue;
            float s = 0.0f;
            for (int j = st; j < en; ++j) {
                int sv = srtS[j];
                s += x[((size_t)b * N + sv) * Cin + c];
            }
            acc = fmaf(s * (1.0f / ((float)(en - st) + 1e-6f)), wv[ky * 3 + kx], acc);
        }
    }
    conv[(size_t)blk * Cin + c] = acc;
}

// ---- fused map2token + skip path as gather; emits bf16 y --------------------
__global__ __launch_bounds__(256) void k_gtok(const float* __restrict__ x,
        const float* __restrict__ conv, const int* __restrict__ off,
        const int* __restrict__ sTs, const int* __restrict__ sTp,
        const float* __restrict__ sTw, const float* __restrict__ skipw,
        unsigned short* __restrict__ ybf) {
    int bt = blockIdx.x;             // b*Nt + t
    int c  = threadIdx.x;
    int b  = bt / Nt;
    int st = off[NBP + bt] - NE, en = off[NBP + bt + 1] - NE;
    float sk = skipw[c];
    float acc = 0.0f, wsum = 0.0f;
    for (int j = st; j < en; ++j) {
        int s = sTs[j], p = sTp[j];
        float w = sTw[j];
        wsum += w;
        acc = fmaf(w, conv[((size_t)b * HWo + p) * Cin + c] + sk * x[((size_t)b * N + s) * Cin + c], acc);
    }
    float v = acc * (1.0f / (wsum + 1e-6f));
    ybf[(size_t)bt * Cin + c] = f2bf(v);
}

// ---- BN1 stats over bf16 y --------------------------------------------------
__global__ void k_ystats(const unsigned short* __restrict__ ybf,
                         float* __restrict__ s1, float* __restrict__ s1q) {
    int c = threadIdx.x;
    float sum = 0.0f, sq = 0.0f;
    for (int r = blockIdx.x; r < RR; r += gridDim.x) {
        float v = bf2f(ybf[(size_t)r * Cin + c]);
        sum += v;
        sq = fmaf(v, v, sq);
    }
    atomicAdd(&s1[c], sum);
    atomicAdd(&s1q[c], sq);
}

// ---- fold BN1 into bf16 weight [Cout][Cin] + fp32 bias ----------------------
__global__ void k_fold(const float* __restrict__ s1, const float* __restrict__ s1q,
                       const float* __restrict__ g1, const float* __restrict__ b1,
                       const float* __restrict__ convw, unsigned short* __restrict__ wfb,
                       float* __restrict__ bias) {
    int o = blockIdx.x, c = threadIdx.x;
    const float inv = 1.0f / (float)RR;
    float mu  = s1[c] * inv;
    float var = s1q[c] * inv - mu * mu;
    float a   = g1[c] / sqrtf(var + 1e-5f);
    float bs  = b1[c] - mu * a;
    float wv  = convw[(size_t)o * Cin + c];
    wfb[(size_t)o * Cin + c] = f2bf(wv * a);
    __shared__ float red[256];
    red[c] = wv * bs;
    __syncthreads();
    for (int st = 128; st > 0; st >>= 1) {
        if (c < st) red[c] += red[c + st];
        __syncthreads();
    }
    if (c == 0) bias[o] = red[0];
}

// ---- bf16 MFMA GEMM: z[RR,512] = ybf[RR,256] @ wfb[512,256]^T + bias --------
typedef __attribute__((ext_vector_type(8))) short short8;
typedef __attribute__((ext_vector_type(4))) float f32x4;

__global__ __launch_bounds__(256) void k_gemm(const unsigned short* __restrict__ A,
        const unsigned short* __restrict__ Bt, const float* __restrict__ bias,
        float* __restrict__ z) {
    constexpr int BK = 32, LS = 48;       // LDS row stride (pad 32->48 to break conflicts)
    __shared__ unsigned short As[128 * LS];
    __shared__ unsigned short Bs[128 * LS];
    int m0 = blockIdx.x * 128, n0 = blockIdx.y * 128;
    int t = threadIdx.x;
    int wave = t >> 6, lane = t & 63;
    int wm = wave >> 1, wn = wave & 1;
    int l16 = lane & 15, lq = lane >> 4;
    f32x4 acc[4][4];
#pragma unroll
    for (int i = 0; i < 4; ++i)
#pragma unroll
        for (int j = 0; j < 4; ++j) acc[i][j] = (f32x4)0.0f;

    for (int k0 = 0; k0 < Cin; k0 += BK) {
#pragma unroll
        for (int r2 = 0; r2 < 2; ++r2) {
            int e = r2 * 256 + t;            // 0..511 chunks of 8 bf16
            int row = e >> 2, kc = (e & 3) * 8;
            *(float4*)&As[row * LS + kc] = *(const float4*)&A[((size_t)(m0 + row)) * Cin + k0 + kc];
            *(float4*)&Bs[row * LS + kc] = *(const float4*)&Bt[((size_t)(n0 + row)) * Cin + k0 + kc];
        }
        __syncthreads();
        short8 af[4], bf[4];
#pragma unroll
        for (int i = 0; i < 4; ++i) {
            af[i] = *(short8*)&As[(wm * 64 + i * 16 + l16) * LS + lq * 8];
            bf[i] = *(short8*)&Bs[(wn * 64 + i * 16 + l16) * LS + lq * 8];
        }
#pragma unroll
        for (int i = 0; i < 4; ++i)
#pragma unroll
            for (int j = 0; j < 4; ++j)
                acc[i][j] = __builtin_amdgcn_mfma_f32_16x16x32_bf16(af[i], bf[j], acc[i][j], 0, 0, 0);
        __syncthreads();
    }
#pragma unroll
    for (int j = 0; j < 4; ++j) {
        int col = n0 + wn * 64 + j * 16 + l16;
        float bv = bias[col];
#pragma unroll
        for (int i = 0; i < 4; ++i) {
            int rbase = m0 + wm * 64 + i * 16 + lq * 4;
#pragma unroll
            for (int r = 0; r < 4; ++r)
                z[(size_t)(rbase + r) * Cout + col] = acc[i][j][r] + bv;
        }
    }
}

// ---- BN2 stats + normalize+ReLU --------------------------------------------
__global__ void k_stats2(const float* __restrict__ z, float* __restrict__ s2,
                         float* __restrict__ s2q) {
    int o = threadIdx.x;   // 0..511
    float sum = 0.0f, sq = 0.0f;
    for (int r = blockIdx.x; r < RR; r += gridDim.x) {
        float v = z[(size_t)r * Cout + o];
        sum += v;
        sq = fmaf(v, v, sq);
    }
    atomicAdd(&s2[o], sum);
    atomicAdd(&s2q[o], sq);
}

__global__ void k_final(float* __restrict__ z, const float* __restrict__ s2,
                        const float* __restrict__ s2q, const float* __restrict__ g2,
                        const float* __restrict__ b2) {
    size_t j = (size_t)blockIdx.x * 256 + threadIdx.x;
    int o = (int)(j & (Cout - 1));
    const float inv = 1.0f / (float)RR;
    float mu  = s2[o] * inv;
    float var = s2q[o] * inv - mu * mu;
    float v = (z[j] - mu) / sqrtf(var + 1e-5f) * g2[o] + b2[o];
    z[j] = fmaxf(v, 0.0f);
}

extern "C" void kernel_launch(void* const* d_in, const int* in_sizes, int n_in,
                              void* d_out, int out_size, void* d_ws, size_t ws_size,
                              hipStream_t stream) {
    const float* x     = (const float*)d_in[0];
    const float* loc   = (const float*)d_in[1];
    const int*   idxa  = (const int*)d_in[2];
    const int*   idxt  = (const int*)d_in[4];
    const float* wt    = (const float*)d_in[5];
    const float* dww   = (const float*)d_in[9];
    const float* skipw = (const float*)d_in[10];
    const float* convw = (const float*)d_in[11];
    const float* g1    = (const float*)d_in[12];
    const float* b1    = (const float*)d_in[13];
    const float* g2    = (const float*)d_in[14];
    const float* b2    = (const float*)d_in[15];

    float* ws = (float*)d_ws;
    int*   hist  = (int*)(ws + W_HIST);
    float* s1sum = ws + W_S1SUM;
    float* s1sq  = ws + W_S1SQ;
    float* s2sum = ws + W_S2SUM;
    float* s2sq  = ws + W_S2SQ;
    int*   off   = (int*)(ws + W_OFF);
    int*   cur   = (int*)(ws + W_CUR);
    int*   p56a  = (int*)(ws + W_P56);
    int*   p28a  = (int*)(ws + W_P28);
    int*   bsum  = (int*)(ws + W_BSUM);
    int*   srtS  = (int*)(ws + W_SRTS);
    int*   sTs   = (int*)(ws + W_STS);
    int*   sTp   = (int*)(ws + W_STP);
    float* sTw   = ws + W_STW;
    float* conv  = ws + W_CONV;
    unsigned short* ybf = (unsigned short*)(ws + W_YBF);
    unsigned short* wfb = (unsigned short*)(ws + W_WFB);
    float* bias  = ws + W_BIAS;
    float* z     = (float*)d_out;

    // zero hist bins + all BN stats (contiguous region)
    hipMemsetAsync(hist, 0, (size_t)(NB + 1536) * sizeof(float), stream);

    k_hist<<<NE / 256, 256, 0, stream>>>(loc, idxt, hist, p56a, p28a);
    k_scanA<<<NCHUNK, 256, 0, stream>>>(hist, bsum);
    k_scanB<<<1, 512, 0, stream>>>(bsum);
    k_scanC<<<NCHUNK, 256, 0, stream>>>(hist, bsum, off, cur);
    k_scatteridx<<<NE / 256, 256, 0, stream>>>(p56a, p28a, idxa, idxt, wt, cur, srtS, sTs, sTp, sTw);

    k_gconv<<<B * HWo, 256, 0, stream>>>(x, off, srtS, dww, conv);
    k_gtok<<<NBT, 256, 0, stream>>>(x, conv, off, sTs, sTp, sTw, skipw, ybf);
    k_ystats<<<256, 256, 0, stream>>>(ybf, s1sum, s1sq);
    k_fold<<<Cout, 256, 0, stream>>>(s1sum, s1sq, g1, b1, convw, wfb, bias);

    dim3 gg(RR / 128, Cout / 128);
    k_gemm<<<gg, 256, 0, stream>>>(ybf, wfb, bias, z);
    k_stats2<<<256, 512, 0, stream>>>(z, s2sum, s2sq);
    k_final<<<(int)(((size_t)RR * Cout) / 256), 256, 0, stream>>>(z, s2sum, s2sq, g2, b2);
}

// Round 3
// 303.115 us; speedup vs baseline: 1.8927x; 1.2020x over previous
//
#include <hip/hip_runtime.h>

// Problem constants
constexpr int B    = 32;
constexpr int N    = 1568;
constexpr int N0   = 3136;
constexpr int Nt   = 784;
constexpr int Cin  = 256;
constexpr int Cout = 512;
constexpr int H    = 56;
constexpr int W    = 56;
constexpr int HW   = 3136;
constexpr int Ho   = 28;
constexpr int Wo   = 28;
constexpr int HWo  = 784;
constexpr int RR   = B * Nt;      // 25088 GEMM rows
constexpr int NE   = B * N0;      // 100352 entries per index list
constexpr int NBP  = B * HW;      // 100352 pixel bins
constexpr int NBT  = B * Nt;      // 25088 token bins
constexpr int NB   = NBP + NBT;   // 125440 bins
constexpr int NCHUNK = NB / 256;  // 490

// Workspace layout (4-byte words). hist + BN stats contiguous -> one memset.
constexpr size_t W_HIST  = 0;                         // NB ints (zeroed)
constexpr size_t W_S1SUM = NB;                        // 256
constexpr size_t W_S1SQ  = W_S1SUM + Cin;             // 256
constexpr size_t W_S2SUM = W_S1SQ + Cin;              // 512
constexpr size_t W_S2SQ  = W_S2SUM + Cout;            // 512 (memset region ends)
constexpr size_t W_OFF   = NB + 1536;                 // NB+1 ints (+pad)
constexpr size_t W_CUR   = W_OFF + NB + 8;            // NB ints
constexpr size_t W_P56   = W_CUR + NB;                // NE ints
constexpr size_t W_P28   = W_P56 + NE;                // NE ints
constexpr size_t W_BSUM  = W_P28 + NE;                // 512 ints
constexpr size_t W_SRTS  = W_BSUM + 512;              // NE ints
constexpr size_t W_STS   = W_SRTS + NE;               // NE ints
constexpr size_t W_STP   = W_STS + NE;                // NE ints
constexpr size_t W_STW   = W_STP + NE;                // NE floats
constexpr size_t W_CONVB = W_STW + NE;                // B*HWo*Cin bf16 -> /2 words
constexpr size_t W_YBF   = W_CONVB + (size_t)B * HWo * Cin / 2;  // RR*Cin bf16
constexpr size_t W_WFB   = W_YBF + (size_t)RR * Cin / 2;         // Cout*Cin bf16
constexpr size_t W_BIAS  = W_WFB + (size_t)Cout * Cin / 2;       // 512
constexpr size_t W_A2    = W_BIAS + Cout;             // 512
constexpr size_t W_C2    = W_A2 + Cout;               // 512
constexpr size_t W_ZB    = W_C2 + Cout;               // RR*Cout bf16 -> /2 words

__device__ __forceinline__ int pix_of(float t, float scale) {
    t = fminf(fmaxf(t, -1.0f), 1.0f);
    float u = __fadd_rn(__fmul_rn(t, 0.5f), 0.5f);   // no fma contraction
    return (int)rintf(__fmul_rn(u, scale));          // round-half-even == jnp.round
}
__device__ __forceinline__ unsigned short f2bf(float f) {
    unsigned int u = __float_as_uint(f);
    u = (u + 0x7fffu + ((u >> 16) & 1u)) >> 16;      // RNE
    return (unsigned short)u;
}
__device__ __forceinline__ float bf2f(unsigned short h) {
    return __uint_as_float(((unsigned int)h) << 16);
}

// ---- sort phase -------------------------------------------------------------
__global__ void k_hist(const float* __restrict__ loc, const int* __restrict__ idxt,
                       int* __restrict__ hist, int* __restrict__ p56a, int* __restrict__ p28a) {
    int i = blockIdx.x * 256 + threadIdx.x;
    if (i >= NE) return;
    int b = i / N0;
    float lx = loc[(size_t)2 * i], ly = loc[(size_t)2 * i + 1];
    int p56 = pix_of(ly, 55.0f) * W + pix_of(lx, 55.0f);
    int p28 = pix_of(ly, 27.0f) * Wo + pix_of(lx, 27.0f);
    p56a[i] = p56; p28a[i] = p28;
    atomicAdd(&hist[b * HW + p56], 1);
    atomicAdd(&hist[NBP + b * Nt + idxt[i]], 1);
}

__global__ void k_scanA(const int* __restrict__ hist, int* __restrict__ bsum) {
    __shared__ int sm[256];
    int i = blockIdx.x * 256 + threadIdx.x;
    sm[threadIdx.x] = hist[i];
    __syncthreads();
    for (int d = 128; d > 0; d >>= 1) {
        if (threadIdx.x < d) sm[threadIdx.x] += sm[threadIdx.x + d];
        __syncthreads();
    }
    if (threadIdx.x == 0) bsum[blockIdx.x] = sm[0];
}

__global__ void k_scanB(int* __restrict__ bsum) {
    __shared__ int sm[512];
    int t = threadIdx.x;
    int v = (t < NCHUNK) ? bsum[t] : 0;
    sm[t] = v; __syncthreads();
    for (int d = 1; d < 512; d <<= 1) {
        int u = (t >= d) ? sm[t - d] : 0;
        __syncthreads();
        sm[t] += u;
        __syncthreads();
    }
    if (t < NCHUNK) bsum[t] = sm[t] - v;
}

__global__ void k_scanC(const int* __restrict__ hist, const int* __restrict__ bsum,
                        int* __restrict__ off, int* __restrict__ cur) {
    __shared__ int sm[256];
    int t = threadIdx.x;
    int i = blockIdx.x * 256 + t;
    int v = hist[i];
    sm[t] = v; __syncthreads();
    for (int d = 1; d < 256; d <<= 1) {
        int u = (t >= d) ? sm[t - d] : 0;
        __syncthreads();
        sm[t] += u;
        __syncthreads();
    }
    int excl = bsum[blockIdx.x] + sm[t] - v;
    off[i] = excl; cur[i] = excl;
    if (i == NB - 1) off[NB] = excl + v;
}

__global__ void k_scatteridx(const int* __restrict__ p56a, const int* __restrict__ p28a,
                             const int* __restrict__ idxa, const int* __restrict__ idxt,
                             const float* __restrict__ wt, int* __restrict__ cur,
                             int* __restrict__ srtS, int* __restrict__ sTs,
                             int* __restrict__ sTp, float* __restrict__ sTw) {
    int i = blockIdx.x * 256 + threadIdx.x;
    if (i >= NE) return;
    int b = i / N0;
    int s = idxa[i];
    int posP = atomicAdd(&cur[b * HW + p56a[i]], 1);
    srtS[posP] = s;
    int posT = atomicAdd(&cur[NBP + b * Nt + idxt[i]], 1) - NE;
    sTs[posT] = s; sTp[posT] = p28a[i]; sTw[posT] = wt[i];
}

// ---- fused token2map + 3x3 dw s2 conv, latency-flattened gather -------------
constexpr int GCAP = 512;
__global__ __launch_bounds__(256) void k_gconv(const float* __restrict__ x,
        const int* __restrict__ off, const int* __restrict__ srtS,
        const float* __restrict__ dww, unsigned short* __restrict__ convb) {
    __shared__ int   sPk[GCAP];
    __shared__ float sRc[GCAP];
    __shared__ int sSt[9], sCt[9], sPref[10];
    int blk = blockIdx.x;            // b*HWo + oy*Wo + ox
    int c   = threadIdx.x;
    int b   = blk / HWo;
    int rem = blk - b * HWo;
    int oy  = rem / Wo;
    int ox  = rem - oy * Wo;
    if (c < 9) {                     // phase 0: all 9 bin ranges in parallel
        int ky = c / 3, kx = c - ky * 3;
        int iy = oy * 2 - 1 + ky, ix = ox * 2 - 1 + kx;
        int st = 0, ct = 0;
        if (iy >= 0 && iy < H && ix >= 0 && ix < W) {
            int bin = b * HW + iy * W + ix;
            st = off[bin];
            ct = off[bin + 1] - st;
        }
        sSt[c] = st; sCt[c] = ct;
    }
    __syncthreads();
    if (c == 0) {
        int a = 0;
#pragma unroll
        for (int k = 0; k < 9; ++k) { sPref[k] = a; a += sCt[k]; }
        sPref[9] = a;
    }
    __syncthreads();
    int T = sPref[9];
    float wv[9];
#pragma unroll
    for (int k = 0; k < 9; ++k) wv[k] = dww[c * 9 + k];
    float acc = 0.0f;
    for (int base = 0; base < T; base += GCAP) {
        if (c < 9) {                 // phase 1: fill contributor list
            int ct = sCt[c], pr = sPref[c], st = sSt[c];
            float rc = 1.0f / ((float)ct + 1e-6f);
            int j0 = max(base - pr, 0);
            int j1 = min(base + GCAP - pr, ct);
            for (int j = j0; j < j1; ++j) {
                sPk[pr + j - base] = srtS[st + j] | (c << 16);
                sRc[pr + j - base] = rc;
            }
        }
        __syncthreads();
        int cnt = min(T - base, GCAP);
        for (int j = 0; j < cnt; ++j) {   // phase 2: independent row gathers
            int pk = sPk[j];
            float rc = sRc[j];
            int s = pk & 0xFFFF, tap = pk >> 16;
            acc = fmaf(x[((size_t)b * N + s) * Cin + c] * rc, wv[tap], acc);
        }
        __syncthreads();
    }
    convb[(size_t)blk * Cin + c] = f2bf(acc);
}

// ---- fused map2token + skip, latency-flattened gather; emits bf16 y ---------
constexpr int TCAP = 256;
__global__ __launch_bounds__(256) void k_gtok(const float* __restrict__ x,
        const unsigned short* __restrict__ convb, const int* __restrict__ off,
        const int* __restrict__ sTs, const int* __restrict__ sTp,
        const float* __restrict__ sTw, const float* __restrict__ skipw,
        unsigned short* __restrict__ ybf) {
    __shared__ int sS[TCAP];
    __shared__ int sP[TCAP];
    __shared__ float sW[TCAP];
    int bt = blockIdx.x;
    int c  = threadIdx.x;
    int b  = bt / Nt;
    int st = off[NBP + bt] - NE, en = off[NBP + bt + 1] - NE;
    int T = en - st;
    float sk = skipw[c];
    float acc = 0.0f, wsum = 0.0f;
    for (int base = 0; base < T; base += TCAP) {
        int cnt = min(T - base, TCAP);
        if (c < cnt) {
            sS[c] = sTs[st + base + c];
            sP[c] = sTp[st + base + c];
            sW[c] = sTw[st + base + c];
        }
        __syncthreads();
        for (int j = 0; j < cnt; ++j) {
            int s = sS[j], p = sP[j];
            float w = sW[j];
            wsum += w;
            float cv = bf2f(convb[((size_t)b * HWo + p) * Cin + c]);
            acc = fmaf(w, cv + sk * x[((size_t)b * N + s) * Cin + c], acc);
        }
        __syncthreads();
    }
    ybf[(size_t)bt * Cin + c] = f2bf(acc * (1.0f / (wsum + 1e-6f)));
}

// ---- BN1 stats over bf16 y --------------------------------------------------
__global__ void k_ystats(const unsigned short* __restrict__ ybf,
                         float* __restrict__ s1, float* __restrict__ s1q) {
    int c = threadIdx.x;
    float sum = 0.0f, sq = 0.0f;
    for (int r = blockIdx.x; r < RR; r += gridDim.x) {
        float v = bf2f(ybf[(size_t)r * Cin + c]);
        sum += v;
        sq = fmaf(v, v, sq);
    }
    atomicAdd(&s1[c], sum);
    atomicAdd(&s1q[c], sq);
}

// ---- fold BN1 into bf16 weight [Cout][Cin] + fp32 bias ----------------------
__global__ void k_fold(const float* __restrict__ s1, const float* __restrict__ s1q,
                       const float* __restrict__ g1, const float* __restrict__ b1,
                       const float* __restrict__ convw, unsigned short* __restrict__ wfb,
                       float* __restrict__ bias) {
    int o = blockIdx.x, c = threadIdx.x;
    const float inv = 1.0f / (float)RR;
    float mu  = s1[c] * inv;
    float var = s1q[c] * inv - mu * mu;
    float a   = g1[c] / sqrtf(var + 1e-5f);
    float bs  = b1[c] - mu * a;
    float wv  = convw[(size_t)o * Cin + c];
    wfb[(size_t)o * Cin + c] = f2bf(wv * a);
    __shared__ float red[256];
    red[c] = wv * bs;
    __syncthreads();
    for (int st = 128; st > 0; st >>= 1) {
        if (c < st) red[c] += red[c + st];
        __syncthreads();
    }
    if (c == 0) bias[o] = red[0];
}

// ---- bf16 MFMA GEMM with fused BN2 stats; bf16 z out ------------------------
typedef __attribute__((ext_vector_type(8))) short short8;
typedef __attribute__((ext_vector_type(4))) float f32x4;

__global__ __launch_bounds__(256) void k_gemm(const unsigned short* __restrict__ A,
        const unsigned short* __restrict__ Bt, const float* __restrict__ bias,
        unsigned short* __restrict__ zb, float* __restrict__ s2, float* __restrict__ s2q) {
    constexpr int BK = 32, LS = 48;
    __shared__ unsigned short As[128 * LS];
    __shared__ unsigned short Bs[128 * LS];
    __shared__ float rsum[128], rsq[128];
    int m0 = blockIdx.x * 128, n0 = blockIdx.y * 128;
    int t = threadIdx.x;
    int wave = t >> 6, lane = t & 63;
    int wm = wave >> 1, wn = wave & 1;
    int l16 = lane & 15, lq = lane >> 4;
    f32x4 acc[4][4];
#pragma unroll
    for (int i = 0; i < 4; ++i)
#pragma unroll
        for (int j = 0; j < 4; ++j) acc[i][j] = (f32x4)0.0f;
    if (t < 128) { rsum[t] = 0.0f; rsq[t] = 0.0f; }

    for (int k0 = 0; k0 < Cin; k0 += BK) {
#pragma unroll
        for (int r2 = 0; r2 < 2; ++r2) {
            int e = r2 * 256 + t;
            int row = e >> 2, kc = (e & 3) * 8;
            *(float4*)&As[row * LS + kc] = *(const float4*)&A[((size_t)(m0 + row)) * Cin + k0 + kc];
            *(float4*)&Bs[row * LS + kc] = *(const float4*)&Bt[((size_t)(n0 + row)) * Cin + k0 + kc];
        }
        __syncthreads();
        short8 af[4], bf[4];
#pragma unroll
        for (int i = 0; i < 4; ++i) {
            af[i] = *(short8*)&As[(wm * 64 + i * 16 + l16) * LS + lq * 8];
            bf[i] = *(short8*)&Bs[(wn * 64 + i * 16 + l16) * LS + lq * 8];
        }
#pragma unroll
        for (int i = 0; i < 4; ++i)
#pragma unroll
            for (int j = 0; j < 4; ++j)
                acc[i][j] = __builtin_amdgcn_mfma_f32_16x16x32_bf16(af[i], bf[j], acc[i][j], 0, 0, 0);
        __syncthreads();
    }
#pragma unroll
    for (int j = 0; j < 4; ++j) {
        int cl  = wn * 64 + j * 16 + l16;     // col within block tile
        int col = n0 + cl;
        float bv = bias[col];
        float ps = 0.0f, pq = 0.0f;
#pragma unroll
        for (int i = 0; i < 4; ++i) {
            int rbase = m0 + wm * 64 + i * 16 + lq * 4;
#pragma unroll
            for (int r = 0; r < 4; ++r) {
                float v = acc[i][j][r] + bv;
                zb[(size_t)(rbase + r) * Cout + col] = f2bf(v);
                ps += v;
                pq = fmaf(v, v, pq);
            }
        }
        atomicAdd(&rsum[cl], ps);
        atomicAdd(&rsq[cl], pq);
    }
    __syncthreads();
    if (t < 128) {
        atomicAdd(&s2[n0 + t], rsum[t]);
        atomicAdd(&s2q[n0 + t], rsq[t]);
    }
}

// ---- BN2 fold: per-channel scale/shift --------------------------------------
__global__ void k_fold2(const float* __restrict__ s2, const float* __restrict__ s2q,
                        const float* __restrict__ g2, const float* __restrict__ b2,
                        float* __restrict__ a2, float* __restrict__ c2) {
    int o = threadIdx.x;   // 512
    const float inv = 1.0f / (float)RR;
    float mu  = s2[o] * inv;
    float var = s2q[o] * inv - mu * mu;
    float a   = g2[o] / sqrtf(var + 1e-5f);
    a2[o] = a;
    c2[o] = b2[o] - mu * a;
}

// ---- BN2 normalize + ReLU: bf16 z -> fp32 out, 4-wide -----------------------
__global__ void k_final(const unsigned short* __restrict__ zb, const float* __restrict__ a2,
                        const float* __restrict__ c2, float* __restrict__ out) {
    size_t j4 = ((size_t)blockIdx.x * 256 + threadIdx.x) * 4;
    int o = (int)(j4 & (Cout - 1));
    uint2 u = *(const uint2*)&zb[j4];
    float e0 = bf2f((unsigned short)(u.x & 0xffffu));
    float e1 = bf2f((unsigned short)(u.x >> 16));
    float e2 = bf2f((unsigned short)(u.y & 0xffffu));
    float e3 = bf2f((unsigned short)(u.y >> 16));
    float4 r;
    r.x = fmaxf(fmaf(e0, a2[o + 0], c2[o + 0]), 0.0f);
    r.y = fmaxf(fmaf(e1, a2[o + 1], c2[o + 1]), 0.0f);
    r.z = fmaxf(fmaf(e2, a2[o + 2], c2[o + 2]), 0.0f);
    r.w = fmaxf(fmaf(e3, a2[o + 3], c2[o + 3]), 0.0f);
    *(float4*)&out[j4] = r;
}

extern "C" void kernel_launch(void* const* d_in, const int* in_sizes, int n_in,
                              void* d_out, int out_size, void* d_ws, size_t ws_size,
                              hipStream_t stream) {
    const float* x     = (const float*)d_in[0];
    const float* loc   = (const float*)d_in[1];
    const int*   idxa  = (const int*)d_in[2];
    const int*   idxt  = (const int*)d_in[4];
    const float* wt    = (const float*)d_in[5];
    const float* dww   = (const float*)d_in[9];
    const float* skipw = (const float*)d_in[10];
    const float* convw = (const float*)d_in[11];
    const float* g1    = (const float*)d_in[12];
    const float* b1    = (const float*)d_in[13];
    const float* g2    = (const float*)d_in[14];
    const float* b2    = (const float*)d_in[15];

    float* ws = (float*)d_ws;
    int*   hist  = (int*)(ws + W_HIST);
    float* s1sum = ws + W_S1SUM;
    float* s1sq  = ws + W_S1SQ;
    float* s2sum = ws + W_S2SUM;
    float* s2sq  = ws + W_S2SQ;
    int*   off   = (int*)(ws + W_OFF);
    int*   cur   = (int*)(ws + W_CUR);
    int*   p56a  = (int*)(ws + W_P56);
    int*   p28a  = (int*)(ws + W_P28);
    int*   bsum  = (int*)(ws + W_BSUM);
    int*   srtS  = (int*)(ws + W_SRTS);
    int*   sTs   = (int*)(ws + W_STS);
    int*   sTp   = (int*)(ws + W_STP);
    float* sTw   = ws + W_STW;
    unsigned short* convb = (unsigned short*)(ws + W_CONVB);
    unsigned short* ybf   = (unsigned short*)(ws + W_YBF);
    unsigned short* wfb   = (unsigned short*)(ws + W_WFB);
    float* bias  = ws + W_BIAS;
    float* a2    = ws + W_A2;
    float* c2    = ws + W_C2;
    unsigned short* zb = (unsigned short*)(ws + W_ZB);
    float* out   = (float*)d_out;

    hipMemsetAsync(hist, 0, (size_t)(NB + 1536) * sizeof(float), stream);

    k_hist<<<NE / 256, 256, 0, stream>>>(loc, idxt, hist, p56a, p28a);
    k_scanA<<<NCHUNK, 256, 0, stream>>>(hist, bsum);
    k_scanB<<<1, 512, 0, stream>>>(bsum);
    k_scanC<<<NCHUNK, 256, 0, stream>>>(hist, bsum, off, cur);
    k_scatteridx<<<NE / 256, 256, 0, stream>>>(p56a, p28a, idxa, idxt, wt, cur, srtS, sTs, sTp, sTw);

    k_gconv<<<B * HWo, 256, 0, stream>>>(x, off, srtS, dww, convb);
    k_gtok<<<NBT, 256, 0, stream>>>(x, convb, off, sTs, sTp, sTw, skipw, ybf);
    k_ystats<<<256, 256, 0, stream>>>(ybf, s1sum, s1sq);
    k_fold<<<Cout, 256, 0, stream>>>(s1sum, s1sq, g1, b1, convw, wfb, bias);

    dim3 gg(RR / 128, Cout / 128);
    k_gemm<<<gg, 256, 0, stream>>>(ybf, wfb, bias, zb, s2sum, s2sq);
    k_fold2<<<1, 512, 0, stream>>>(s2sum, s2sq, g2, b2, a2, c2);
    k_final<<<(int)(((size_t)RR * Cout) / 1024), 256, 0, stream>>>(zb, a2, c2, out);
}